// Round 1
// baseline (642.626 us; speedup 1.0000x reference)
//
#include <hip/hip_runtime.h>
#include <math.h>

#define N_NODESC 50000
#define N_EDGESC 800000
#define N_GRAPHSC 16
#define IN_CC 5
#define HIDC 128
#define OUTCC 64

// derived-weight buffer layout (floats)
#define DW_WAS1 0
#define DW_WAD1 5
#define DW_WEAE1 10
#define DW_WEAE2 13
#define DW_WAS2 16
#define DW_WAD2 144
#define DW_TOTAL 272

__device__ __forceinline__ float leakyf(float x) { return x >= 0.0f ? x : 0.2f * x; }

// ---------------- derived weights: W@a_s, W@a_d, We@ae ----------------
__global__ void k_derived(const float* __restrict__ W1, const float* __restrict__ as1,
                          const float* __restrict__ ad1, const float* __restrict__ We1,
                          const float* __restrict__ ae1, const float* __restrict__ W2,
                          const float* __restrict__ as2, const float* __restrict__ ad2,
                          const float* __restrict__ We2, const float* __restrict__ ae2,
                          float* __restrict__ dw) {
    for (int t = threadIdx.x; t < DW_TOTAL; t += blockDim.x) {
        float acc = 0.0f;
        if (t < 5) {
            for (int c = 0; c < HIDC; ++c) acc += W1[t * HIDC + c] * as1[c];
        } else if (t < 10) {
            int k = t - 5;
            for (int c = 0; c < HIDC; ++c) acc += W1[k * HIDC + c] * ad1[c];
        } else if (t < 13) {
            int j = t - 10;
            for (int c = 0; c < HIDC; ++c) acc += We1[j * HIDC + c] * ae1[c];
        } else if (t < 16) {
            int j = t - 13;
            for (int c = 0; c < OUTCC; ++c) acc += We2[j * OUTCC + c] * ae2[c];
        } else if (t < 144) {
            int k = t - 16;
            for (int c = 0; c < OUTCC; ++c) acc += W2[k * OUTCC + c] * as2[c];
        } else {
            int k = t - 144;
            for (int c = 0; c < OUTCC; ++c) acc += W2[k * OUTCC + c] * ad2[c];
        }
        dw[t] = acc;
    }
}

// ---------------- edge counting + loop_attr sum ----------------
__global__ void k_count(const int* __restrict__ ei, const float* __restrict__ eattr,
                        int* __restrict__ cnt, float* __restrict__ lsum) {
    int e = blockIdx.x * blockDim.x + threadIdx.x;
    if (e >= N_EDGESC) return;
    int d = ei[N_EDGESC + e];
    atomicAdd(&cnt[d], 1);
    atomicAdd(&lsum[d * 3 + 0], eattr[e * 3 + 0]);
    atomicAdd(&lsum[d * 3 + 1], eattr[e * 3 + 1]);
    atomicAdd(&lsum[d * 3 + 2], eattr[e * 3 + 2]);
}

// ---------------- single-block exclusive scan over cnt -> rowptr ----------------
__global__ void k_scan(const int* __restrict__ cnt, int* __restrict__ rowptr) {
    __shared__ int s[1024];
    __shared__ int carry_s;
    int tid = threadIdx.x;
    if (tid == 0) carry_s = 0;
    __syncthreads();
    for (int base = 0; base < N_NODESC; base += 1024) {
        int idx = base + tid;
        int v = (idx < N_NODESC) ? cnt[idx] : 0;
        s[tid] = v;
        __syncthreads();
        for (int off = 1; off < 1024; off <<= 1) {
            int t = (tid >= off) ? s[tid - off] : 0;
            __syncthreads();
            s[tid] += t;
            __syncthreads();
        }
        int incl = s[tid];
        if (idx < N_NODESC) rowptr[idx] = carry_s + incl - v;
        __syncthreads();
        if (tid == 1023) carry_s = carry_s + incl;
        __syncthreads();
    }
    if (tid == 0) rowptr[N_NODESC] = carry_s;
}

// ---------------- scatter edges into dst-sorted order ----------------
__global__ void k_scatter(const int* __restrict__ ei, const float* __restrict__ eattr,
                          const int* __restrict__ rowptr, int* __restrict__ cursor,
                          int* __restrict__ src_sorted, float* __restrict__ eal1,
                          float* __restrict__ eal2, const float* __restrict__ dw) {
    int e = blockIdx.x * blockDim.x + threadIdx.x;
    if (e >= N_EDGESC) return;
    int d = ei[N_EDGESC + e];
    int pos = rowptr[d] + atomicAdd(&cursor[d], 1);
    src_sorted[pos] = ei[e];
    float a0 = eattr[e * 3 + 0], a1 = eattr[e * 3 + 1], a2 = eattr[e * 3 + 2];
    eal1[pos] = a0 * dw[DW_WEAE1 + 0] + a1 * dw[DW_WEAE1 + 1] + a2 * dw[DW_WEAE1 + 2];
    eal2[pos] = a0 * dw[DW_WEAE2 + 0] + a1 * dw[DW_WEAE2 + 1] + a2 * dw[DW_WEAE2 + 2];
}

// ---------------- self-loop attention-logit contribution ----------------
__global__ void k_loop_al(const int* __restrict__ cnt, const float* __restrict__ lsum,
                          const float* __restrict__ dw, float* __restrict__ la1,
                          float* __restrict__ la2) {
    int n = blockIdx.x * blockDim.x + threadIdx.x;
    if (n >= N_NODESC) return;
    float inv = 1.0f / fmaxf((float)cnt[n], 1.0f);
    float s0 = lsum[n * 3 + 0], s1 = lsum[n * 3 + 1], s2 = lsum[n * 3 + 2];
    la1[n] = (s0 * dw[DW_WEAE1 + 0] + s1 * dw[DW_WEAE1 + 1] + s2 * dw[DW_WEAE1 + 2]) * inv;
    la2[n] = (s0 * dw[DW_WEAE2 + 0] + s1 * dw[DW_WEAE2 + 1] + s2 * dw[DW_WEAE2 + 2]) * inv;
}

// ---------------- h1 = x @ W1  (thread per (n,c)) ----------------
__global__ void k_h1(const float* __restrict__ x, const float* __restrict__ W1,
                     float* __restrict__ h1) {
    int t = blockIdx.x * blockDim.x + threadIdx.x;
    int n = t >> 7, c = t & 127;
    if (n >= N_NODESC) return;
    float acc = 0.0f;
#pragma unroll
    for (int k = 0; k < IN_CC; ++k) acc += x[n * IN_CC + k] * W1[k * HIDC + c];
    h1[t] = acc;
}

// ---------------- alpha_s1/alpha_d1 = x @ (W1@a) ----------------
__global__ void k_alpha1(const float* __restrict__ x, const float* __restrict__ dw,
                         float* __restrict__ as1v, float* __restrict__ ad1v) {
    int n = blockIdx.x * blockDim.x + threadIdx.x;
    if (n >= N_NODESC) return;
    float a = 0.0f, b = 0.0f;
#pragma unroll
    for (int k = 0; k < IN_CC; ++k) {
        float xv = x[n * IN_CC + k];
        a += xv * dw[DW_WAS1 + k];
        b += xv * dw[DW_WAD1 + k];
    }
    as1v[n] = a;
    ad1v[n] = b;
}

// ---------------- main per-node softmax + gather-aggregate ----------------
template <int C>
__global__ void k_agg(const float* __restrict__ h, const float* __restrict__ alpha_s,
                      const float* __restrict__ alpha_d, const float* __restrict__ eal,
                      const float* __restrict__ loop_al, const int* __restrict__ rowptr,
                      const int* __restrict__ src_sorted, const float* __restrict__ bias,
                      float* __restrict__ out, int do_relu) {
    int gid = blockIdx.x * blockDim.x + threadIdx.x;
    int n = gid >> 6;
    int lane = threadIdx.x & 63;
    if (n >= N_NODESC) return;
    int off = rowptr[n];
    int deg = rowptr[n + 1] - off;
    float ad = alpha_d[n];
    float lself = leakyf(alpha_s[n] + ad + loop_al[n]);
    float m = lself, den = 1.0f;
    for (int base = 0; base < deg; base += 64) {
        int i = base + lane;
        bool valid = i < deg;
        float l = -1e30f;
        if (valid) {
            int s = src_sorted[off + i];
            l = leakyf(alpha_s[s] + ad + eal[off + i]);
        }
        float cm = l;
#pragma unroll
        for (int d = 32; d; d >>= 1) cm = fmaxf(cm, __shfl_xor(cm, d));
        float nm = fmaxf(m, cm);
        float ex = valid ? __expf(l - nm) : 0.0f;
#pragma unroll
        for (int d = 32; d; d >>= 1) ex += __shfl_xor(ex, d);
        den = den * __expf(m - nm) + ex;
        m = nm;
    }
    float inv_den = 1.0f / den;
    float coef_self = __expf(lself - m) * inv_den;
    float acc0 = coef_self * h[n * C + lane];
    float acc1 = 0.0f;
    if (C == 128) acc1 = coef_self * h[n * C + 64 + lane];
    for (int i = 0; i < deg; ++i) {
        int s = src_sorted[off + i];
        float l = leakyf(alpha_s[s] + ad + eal[off + i]);
        float coef = __expf(l - m) * inv_den;
        acc0 += coef * h[s * C + lane];
        if (C == 128) acc1 += coef * h[s * C + 64 + lane];
    }
    float o0 = acc0 + bias[lane];
    if (do_relu) o0 = fmaxf(o0, 0.0f);
    out[n * C + lane] = o0;
    if (C == 128) {
        float o1 = acc1 + bias[64 + lane];
        if (do_relu) o1 = fmaxf(o1, 0.0f);
        out[n * C + 64 + lane] = o1;
    }
}

// ---------------- h2 = x2 @ W2 (LDS-staged W2, wave per node) ----------------
__global__ void k_h2(const float* __restrict__ x2, const float* __restrict__ W2,
                     float* __restrict__ h2) {
    __shared__ float w2s[HIDC * OUTCC];
    int tid = threadIdx.x;
    for (int i = tid; i < HIDC * OUTCC; i += 256) w2s[i] = W2[i];
    __syncthreads();
    int c = tid & 63, sub = tid >> 6;
    for (int rep = 0; rep < 2; ++rep) {
        int n = blockIdx.x * 8 + rep * 4 + sub;
        if (n >= N_NODESC) continue;
        const float* xr = x2 + (size_t)n * HIDC;
        float acc = 0.0f;
#pragma unroll 4
        for (int k = 0; k < HIDC; ++k) acc += xr[k] * w2s[k * OUTCC + c];
        h2[n * OUTCC + c] = acc;
    }
}

// ---------------- alpha_s2/alpha_d2 = x2 @ (W2@a) (wave per node) ----------------
__global__ void k_alpha2(const float* __restrict__ x2, const float* __restrict__ dw,
                         float* __restrict__ as2v, float* __restrict__ ad2v) {
    int gid = blockIdx.x * blockDim.x + threadIdx.x;
    int wid = gid >> 6;
    int lane = threadIdx.x & 63;
    if (wid >= N_NODESC) return;
    const float* xr = x2 + (size_t)wid * HIDC;
    float xa = xr[lane], xb = xr[lane + 64];
    float a = xa * dw[DW_WAS2 + lane] + xb * dw[DW_WAS2 + lane + 64];
    float b = xa * dw[DW_WAD2 + lane] + xb * dw[DW_WAD2 + lane + 64];
#pragma unroll
    for (int d = 32; d; d >>= 1) {
        a += __shfl_xor(a, d);
        b += __shfl_xor(b, d);
    }
    if (lane == 0) {
        as2v[wid] = a;
        ad2v[wid] = b;
    }
}

// ---------------- mean pool: partial sums per 64-node chunk ----------------
__global__ void k_pool(const float* __restrict__ out2, const int* __restrict__ batch,
                       float* __restrict__ dout) {
    int lane = threadIdx.x;  // blockDim = 64
    int base = blockIdx.x * 64;
    float acc = 0.0f;
    int curg = batch[base];
    for (int i = 0; i < 64; ++i) {
        int n = base + i;
        if (n >= N_NODESC) break;
        int g = batch[n];
        if (g != curg) {
            atomicAdd(&dout[curg * OUTCC + lane], acc);
            acc = 0.0f;
            curg = g;
        }
        acc += out2[n * OUTCC + lane];
    }
    atomicAdd(&dout[curg * OUTCC + lane], acc);
}

// ---------------- divide by per-graph node count (binary search on sorted batch) ----------------
__global__ void k_finalize(const int* __restrict__ batch, float* __restrict__ dout) {
    int t = blockIdx.x * blockDim.x + threadIdx.x;
    if (t >= N_GRAPHSC * OUTCC) return;
    int g = t >> 6;
    int lo = 0, hi = N_NODESC;
    while (lo < hi) {
        int mid = (lo + hi) >> 1;
        if (batch[mid] < g) lo = mid + 1; else hi = mid;
    }
    int start = lo;
    lo = 0; hi = N_NODESC;
    while (lo < hi) {
        int mid = (lo + hi) >> 1;
        if (batch[mid] <= g) lo = mid + 1; else hi = mid;
    }
    int cntg = lo - start;
    dout[t] = dout[t] / fmaxf((float)cntg, 1.0f);
}

extern "C" void kernel_launch(void* const* d_in, const int* in_sizes, int n_in,
                              void* d_out, int out_size, void* d_ws, size_t ws_size,
                              hipStream_t stream) {
    const float* x     = (const float*)d_in[0];
    const int*   ei    = (const int*)d_in[1];
    const float* eattr = (const float*)d_in[2];
    const int*   batch = (const int*)d_in[3];
    const float* W1  = (const float*)d_in[4];
    const float* as1 = (const float*)d_in[5];
    const float* ad1 = (const float*)d_in[6];
    const float* We1 = (const float*)d_in[7];
    const float* ae1 = (const float*)d_in[8];
    const float* b1  = (const float*)d_in[9];
    const float* W2  = (const float*)d_in[10];
    const float* as2 = (const float*)d_in[11];
    const float* ad2 = (const float*)d_in[12];
    const float* We2 = (const float*)d_in[13];
    const float* ae2 = (const float*)d_in[14];
    const float* b2  = (const float*)d_in[15];
    float* out = (float*)d_out;

    char* ws = (char*)d_ws;
    size_t off = 0;
    auto alloc = [&](size_t bytes) -> void* {
        void* p = ws + off;
        off = (off + bytes + 255) & ~(size_t)255;
        return p;
    };
    float* dw        = (float*)alloc(DW_TOTAL * 4);
    int*   cnt       = (int*)alloc(N_NODESC * 4);
    int*   cursor    = (int*)alloc(N_NODESC * 4);
    int*   rowptr    = (int*)alloc((N_NODESC + 1) * 4);
    int*   src_sorted= (int*)alloc((size_t)N_EDGESC * 4);
    float* eal1      = (float*)alloc((size_t)N_EDGESC * 4);
    float* eal2      = (float*)alloc((size_t)N_EDGESC * 4);
    float* lsum      = (float*)alloc((size_t)N_NODESC * 3 * 4);
    float* la1       = (float*)alloc(N_NODESC * 4);
    float* la2       = (float*)alloc(N_NODESC * 4);
    float* as1v      = (float*)alloc(N_NODESC * 4);
    float* ad1v      = (float*)alloc(N_NODESC * 4);
    float* as2v      = (float*)alloc(N_NODESC * 4);
    float* ad2v      = (float*)alloc(N_NODESC * 4);
    float* h1        = (float*)alloc((size_t)N_NODESC * HIDC * 4);
    float* x2        = (float*)alloc((size_t)N_NODESC * HIDC * 4);
    float* h2        = (float*)alloc((size_t)N_NODESC * OUTCC * 4);
    float* out2      = (float*)alloc((size_t)N_NODESC * OUTCC * 4);

    hipMemsetAsync(cnt, 0, N_NODESC * 4, stream);
    hipMemsetAsync(cursor, 0, N_NODESC * 4, stream);
    hipMemsetAsync(lsum, 0, (size_t)N_NODESC * 3 * 4, stream);
    hipMemsetAsync(out, 0, N_GRAPHSC * OUTCC * 4, stream);

    k_derived<<<1, 256, 0, stream>>>(W1, as1, ad1, We1, ae1, W2, as2, ad2, We2, ae2, dw);
    k_count<<<(N_EDGESC + 255) / 256, 256, 0, stream>>>(ei, eattr, cnt, lsum);
    k_scan<<<1, 1024, 0, stream>>>(cnt, rowptr);
    k_scatter<<<(N_EDGESC + 255) / 256, 256, 0, stream>>>(ei, eattr, rowptr, cursor,
                                                          src_sorted, eal1, eal2, dw);
    k_loop_al<<<(N_NODESC + 255) / 256, 256, 0, stream>>>(cnt, lsum, dw, la1, la2);
    k_h1<<<(N_NODESC * HIDC) / 256, 256, 0, stream>>>(x, W1, h1);
    k_alpha1<<<(N_NODESC + 255) / 256, 256, 0, stream>>>(x, dw, as1v, ad1v);
    k_agg<HIDC><<<(N_NODESC * 64) / 256, 256, 0, stream>>>(h1, as1v, ad1v, eal1, la1, rowptr,
                                                           src_sorted, b1, x2, 1);
    k_h2<<<(N_NODESC + 7) / 8, 256, 0, stream>>>(x2, W2, h2);
    k_alpha2<<<(N_NODESC * 64) / 256, 256, 0, stream>>>(x2, dw, as2v, ad2v);
    k_agg<OUTCC><<<(N_NODESC * 64) / 256, 256, 0, stream>>>(h2, as2v, ad2v, eal2, la2, rowptr,
                                                            src_sorted, b2, out2, 0);
    k_pool<<<(N_NODESC + 63) / 64, 64, 0, stream>>>(out2, batch, out);
    k_finalize<<<4, 256, 0, stream>>>(batch, out);
}

// Round 2
// 370.836 us; speedup vs baseline: 1.7329x; 1.7329x over previous
//
#include <hip/hip_runtime.h>
#include <math.h>

#define N_NODESC 50000
#define N_EDGESC 800000
#define N_GRAPHSC 16
#define IN_CC 5
#define HIDC 128
#define OUTCC 64

#define SCAN_B 1024
#define NBLK ((N_NODESC + SCAN_B - 1) / SCAN_B)  // 49

// derived-weight buffer layout (floats)
#define DW_WAS1 0
#define DW_WAD1 5
#define DW_WEAE1 10
#define DW_WEAE2 13
#define DW_WAS2 16
#define DW_WAD2 144
#define DW_TOTAL 272

__device__ __forceinline__ float leakyf(float x) { return x >= 0.0f ? x : 0.2f * x; }

// ---------------- derived weights: W@a_s, W@a_d, We@ae ----------------
__global__ void k_derived(const float* __restrict__ W1, const float* __restrict__ as1,
                          const float* __restrict__ ad1, const float* __restrict__ We1,
                          const float* __restrict__ ae1, const float* __restrict__ W2,
                          const float* __restrict__ as2, const float* __restrict__ ad2,
                          const float* __restrict__ We2, const float* __restrict__ ae2,
                          float* __restrict__ dw) {
    for (int t = threadIdx.x; t < DW_TOTAL; t += blockDim.x) {
        float acc = 0.0f;
        if (t < 5) {
            for (int c = 0; c < HIDC; ++c) acc += W1[t * HIDC + c] * as1[c];
        } else if (t < 10) {
            int k = t - 5;
            for (int c = 0; c < HIDC; ++c) acc += W1[k * HIDC + c] * ad1[c];
        } else if (t < 13) {
            int j = t - 10;
            for (int c = 0; c < HIDC; ++c) acc += We1[j * HIDC + c] * ae1[c];
        } else if (t < 16) {
            int j = t - 13;
            for (int c = 0; c < OUTCC; ++c) acc += We2[j * OUTCC + c] * ae2[c];
        } else if (t < 144) {
            int k = t - 16;
            for (int c = 0; c < OUTCC; ++c) acc += W2[k * OUTCC + c] * as2[c];
        } else {
            int k = t - 144;
            for (int c = 0; c < OUTCC; ++c) acc += W2[k * OUTCC + c] * ad2[c];
        }
        dw[t] = acc;
    }
}

// ---------------- edge counting (single int atomic per edge) ----------------
__global__ void k_count(const int* __restrict__ ei, int* __restrict__ cnt) {
    int e = blockIdx.x * blockDim.x + threadIdx.x;
    if (e >= N_EDGESC) return;
    atomicAdd(&cnt[ei[N_EDGESC + e]], 1);
}

// ---------------- hierarchical exclusive scan: cnt -> rowptr ----------------
__global__ void k_scan1(const int* __restrict__ cnt, int* __restrict__ rp,
                        int* __restrict__ bsum) {
    __shared__ int s[SCAN_B];
    int tid = threadIdx.x;
    int idx = blockIdx.x * SCAN_B + tid;
    int v = (idx < N_NODESC) ? cnt[idx] : 0;
    s[tid] = v;
    __syncthreads();
    for (int off = 1; off < SCAN_B; off <<= 1) {
        int t = (tid >= off) ? s[tid - off] : 0;
        __syncthreads();
        s[tid] += t;
        __syncthreads();
    }
    if (idx < N_NODESC) rp[idx] = s[tid] - v;  // exclusive within block
    if (tid == SCAN_B - 1) bsum[blockIdx.x] = s[tid];
}

__global__ void k_scan2(const int* __restrict__ bsum, int* __restrict__ btop) {
    int lane = threadIdx.x;  // one wave
    int orig = (lane < NBLK) ? bsum[lane] : 0;
    int v = orig;
#pragma unroll
    for (int off = 1; off < 64; off <<= 1) {
        int t = __shfl_up(v, off);
        if (lane >= off) v += t;
    }
    if (lane < NBLK) btop[lane] = v - orig;  // exclusive
}

__global__ void k_scan3(int* __restrict__ rp, const int* __restrict__ btop) {
    int idx = blockIdx.x * SCAN_B + threadIdx.x;
    if (idx < N_NODESC) rp[idx] += btop[blockIdx.x];
    if (idx == 0) rp[N_NODESC] = N_EDGESC;
}

// ---------------- scatter edges into dst-sorted order (cnt reused as cursor) ----------------
__global__ void k_scatter(const int* __restrict__ ei, const float* __restrict__ eattr,
                          const int* __restrict__ rowptr, int* __restrict__ cnt,
                          int* __restrict__ src_sorted, float* __restrict__ eal1,
                          float* __restrict__ eal2, const float* __restrict__ dw) {
    int e = blockIdx.x * blockDim.x + threadIdx.x;
    if (e >= N_EDGESC) return;
    int d = ei[N_EDGESC + e];
    int pos = rowptr[d] + atomicSub(&cnt[d], 1) - 1;
    src_sorted[pos] = ei[e];
    float a0 = eattr[e * 3 + 0], a1 = eattr[e * 3 + 1], a2 = eattr[e * 3 + 2];
    eal1[pos] = a0 * dw[DW_WEAE1 + 0] + a1 * dw[DW_WEAE1 + 1] + a2 * dw[DW_WEAE1 + 2];
    eal2[pos] = a0 * dw[DW_WEAE2 + 0] + a1 * dw[DW_WEAE2 + 1] + a2 * dw[DW_WEAE2 + 2];
}

// ---------------- h1 = x @ W1  (thread per (n,c)) ----------------
__global__ void k_h1(const float* __restrict__ x, const float* __restrict__ W1,
                     float* __restrict__ h1) {
    int t = blockIdx.x * blockDim.x + threadIdx.x;
    int n = t >> 7, c = t & 127;
    if (n >= N_NODESC) return;
    float acc = 0.0f;
#pragma unroll
    for (int k = 0; k < IN_CC; ++k) acc += x[n * IN_CC + k] * W1[k * HIDC + c];
    h1[t] = acc;
}

// ---------------- alpha_s1/alpha_d1 = x @ (W1@a) ----------------
__global__ void k_alpha1(const float* __restrict__ x, const float* __restrict__ dw,
                         float* __restrict__ as1v, float* __restrict__ ad1v) {
    int n = blockIdx.x * blockDim.x + threadIdx.x;
    if (n >= N_NODESC) return;
    float a = 0.0f, b = 0.0f;
#pragma unroll
    for (int k = 0; k < IN_CC; ++k) {
        float xv = x[n * IN_CC + k];
        a += xv * dw[DW_WAS1 + k];
        b += xv * dw[DW_WAD1 + k];
    }
    as1v[n] = a;
    ad1v[n] = b;
}

// ---------------- single-pass flash-style softmax + gather-aggregate ----------------
// self-loop logit term = mean(eal over incoming edges) (algebraic identity),
// merged at the end. For C==128, also emits alpha_s2/alpha_d2 (fused epilogue).
template <int C>
__global__ void k_agg(const float* __restrict__ h, const float* __restrict__ alpha_s,
                      const float* __restrict__ alpha_d, const float* __restrict__ eal,
                      const int* __restrict__ rowptr, const int* __restrict__ src_sorted,
                      const float* __restrict__ bias, const float* __restrict__ dw,
                      float* __restrict__ out, float* __restrict__ as2v,
                      float* __restrict__ ad2v, int do_relu) {
    int gid = blockIdx.x * blockDim.x + threadIdx.x;
    int n = gid >> 6;
    int lane = threadIdx.x & 63;
    if (n >= N_NODESC) return;
    int off = rowptr[n];
    int deg = rowptr[n + 1] - off;
    float ad = alpha_d[n];
    float m = -1e30f, den = 0.0f, acc0 = 0.0f, acc1 = 0.0f, sum_eal = 0.0f;
    for (int base = 0; base < deg; base += 64) {
        int i = base + lane;
        bool valid = i < deg;
        int s = valid ? src_sorted[off + i] : 0;
        float ev = valid ? eal[off + i] : 0.0f;
        float l = valid ? leakyf(alpha_s[s] + ad + ev) : -1e30f;
        sum_eal += ev;
        float cm = l;
#pragma unroll
        for (int d2 = 32; d2; d2 >>= 1) cm = fmaxf(cm, __shfl_xor(cm, d2));
        float nm = fmaxf(m, cm);
        float scale = __expf(m - nm);
        float ex = valid ? __expf(l - nm) : 0.0f;
        float exs = ex;
#pragma unroll
        for (int d2 = 32; d2; d2 >>= 1) exs += __shfl_xor(exs, d2);
        den = den * scale + exs;
        acc0 *= scale;
        if (C == 128) acc1 *= scale;
        m = nm;
        int lim = min(64, deg - base);
#pragma unroll 4
        for (int i2 = 0; i2 < lim; ++i2) {
            float c = __shfl(ex, i2);
            int s2 = __shfl(s, i2);
            acc0 += c * h[(size_t)s2 * C + lane];
            if (C == 128) acc1 += c * h[(size_t)s2 * C + 64 + lane];
        }
    }
#pragma unroll
    for (int d2 = 32; d2; d2 >>= 1) sum_eal += __shfl_xor(sum_eal, d2);
    float la = sum_eal / fmaxf((float)deg, 1.0f);
    float lself = leakyf(alpha_s[n] + ad + la);
    float nm = fmaxf(m, lself);
    float scale = __expf(m - nm);
    float es = __expf(lself - nm);
    den = den * scale + es;
    acc0 = acc0 * scale + es * h[(size_t)n * C + lane];
    if (C == 128) acc1 = acc1 * scale + es * h[(size_t)n * C + 64 + lane];
    float inv = 1.0f / den;
    float o0 = acc0 * inv + bias[lane];
    if (do_relu) o0 = fmaxf(o0, 0.0f);
    out[(size_t)n * C + lane] = o0;
    if (C == 128) {
        float o1 = acc1 * inv + bias[64 + lane];
        if (do_relu) o1 = fmaxf(o1, 0.0f);
        out[(size_t)n * C + 64 + lane] = o1;
        // fused alpha_s2/alpha_d2 = x2_row @ (W2@a)
        float a = o0 * dw[DW_WAS2 + lane] + o1 * dw[DW_WAS2 + 64 + lane];
        float b = o0 * dw[DW_WAD2 + lane] + o1 * dw[DW_WAD2 + 64 + lane];
#pragma unroll
        for (int d2 = 32; d2; d2 >>= 1) {
            a += __shfl_xor(a, d2);
            b += __shfl_xor(b, d2);
        }
        if (lane == 0) {
            as2v[n] = a;
            ad2v[n] = b;
        }
    }
}

// ---------------- h2 = x2 @ W2 (LDS-staged W2) ----------------
__global__ void k_h2(const float* __restrict__ x2, const float* __restrict__ W2,
                     float* __restrict__ h2) {
    __shared__ float w2s[HIDC * OUTCC];
    int tid = threadIdx.x;
    for (int i = tid; i < HIDC * OUTCC; i += 256) w2s[i] = W2[i];
    __syncthreads();
    int c = tid & 63, sub = tid >> 6;
    for (int rep = 0; rep < 2; ++rep) {
        int n = blockIdx.x * 8 + rep * 4 + sub;
        if (n >= N_NODESC) continue;
        const float* xr = x2 + (size_t)n * HIDC;
        float acc = 0.0f;
#pragma unroll 4
        for (int k = 0; k < HIDC; ++k) acc += xr[k] * w2s[k * OUTCC + c];
        h2[n * OUTCC + c] = acc;
    }
}

// ---------------- mean pool: partial sums per 64-node chunk ----------------
__global__ void k_pool(const float* __restrict__ out2, const int* __restrict__ batch,
                       float* __restrict__ dout) {
    int lane = threadIdx.x;  // blockDim = 64
    int base = blockIdx.x * 64;
    float acc = 0.0f;
    int curg = batch[base];
    for (int i = 0; i < 64; ++i) {
        int n = base + i;
        if (n >= N_NODESC) break;
        int g = batch[n];
        if (g != curg) {
            atomicAdd(&dout[curg * OUTCC + lane], acc);
            acc = 0.0f;
            curg = g;
        }
        acc += out2[n * OUTCC + lane];
    }
    atomicAdd(&dout[curg * OUTCC + lane], acc);
}

// ---------------- divide by per-graph node count ----------------
__global__ void k_finalize(const int* __restrict__ batch, float* __restrict__ dout) {
    int t = blockIdx.x * blockDim.x + threadIdx.x;
    if (t >= N_GRAPHSC * OUTCC) return;
    int g = t >> 6;
    int lo = 0, hi = N_NODESC;
    while (lo < hi) {
        int mid = (lo + hi) >> 1;
        if (batch[mid] < g) lo = mid + 1; else hi = mid;
    }
    int start = lo;
    lo = 0; hi = N_NODESC;
    while (lo < hi) {
        int mid = (lo + hi) >> 1;
        if (batch[mid] <= g) lo = mid + 1; else hi = mid;
    }
    int cntg = lo - start;
    dout[t] = dout[t] / fmaxf((float)cntg, 1.0f);
}

extern "C" void kernel_launch(void* const* d_in, const int* in_sizes, int n_in,
                              void* d_out, int out_size, void* d_ws, size_t ws_size,
                              hipStream_t stream) {
    const float* x     = (const float*)d_in[0];
    const int*   ei    = (const int*)d_in[1];
    const float* eattr = (const float*)d_in[2];
    const int*   batch = (const int*)d_in[3];
    const float* W1  = (const float*)d_in[4];
    const float* as1 = (const float*)d_in[5];
    const float* ad1 = (const float*)d_in[6];
    const float* We1 = (const float*)d_in[7];
    const float* ae1 = (const float*)d_in[8];
    const float* b1  = (const float*)d_in[9];
    const float* W2  = (const float*)d_in[10];
    const float* as2 = (const float*)d_in[11];
    const float* ad2 = (const float*)d_in[12];
    const float* We2 = (const float*)d_in[13];
    const float* ae2 = (const float*)d_in[14];
    const float* b2  = (const float*)d_in[15];
    float* out = (float*)d_out;

    char* ws = (char*)d_ws;
    size_t off = 0;
    auto alloc = [&](size_t bytes) -> void* {
        void* p = ws + off;
        off = (off + bytes + 255) & ~(size_t)255;
        return p;
    };
    float* dw        = (float*)alloc(DW_TOTAL * 4);
    int*   cnt       = (int*)alloc(N_NODESC * 4);
    int*   rowptr    = (int*)alloc((N_NODESC + 1) * 4);
    int*   bsum      = (int*)alloc(NBLK * 4);
    int*   btop      = (int*)alloc(NBLK * 4);
    int*   src_sorted= (int*)alloc((size_t)N_EDGESC * 4);
    float* eal1      = (float*)alloc((size_t)N_EDGESC * 4);
    float* eal2      = (float*)alloc((size_t)N_EDGESC * 4);
    float* as1v      = (float*)alloc(N_NODESC * 4);
    float* ad1v      = (float*)alloc(N_NODESC * 4);
    float* as2v      = (float*)alloc(N_NODESC * 4);
    float* ad2v      = (float*)alloc(N_NODESC * 4);
    float* h1        = (float*)alloc((size_t)N_NODESC * HIDC * 4);
    float* x2        = (float*)alloc((size_t)N_NODESC * HIDC * 4);
    float* h2        = (float*)alloc((size_t)N_NODESC * OUTCC * 4);
    float* out2      = (float*)alloc((size_t)N_NODESC * OUTCC * 4);

    hipMemsetAsync(cnt, 0, N_NODESC * 4, stream);
    hipMemsetAsync(out, 0, N_GRAPHSC * OUTCC * 4, stream);

    k_derived<<<1, 256, 0, stream>>>(W1, as1, ad1, We1, ae1, W2, as2, ad2, We2, ae2, dw);
    k_count<<<(N_EDGESC + 255) / 256, 256, 0, stream>>>(ei, cnt);
    k_scan1<<<NBLK, SCAN_B, 0, stream>>>(cnt, rowptr, bsum);
    k_scan2<<<1, 64, 0, stream>>>(bsum, btop);
    k_scan3<<<NBLK, SCAN_B, 0, stream>>>(rowptr, btop);
    k_scatter<<<(N_EDGESC + 255) / 256, 256, 0, stream>>>(ei, eattr, rowptr, cnt,
                                                          src_sorted, eal1, eal2, dw);
    k_h1<<<(N_NODESC * HIDC) / 256, 256, 0, stream>>>(x, W1, h1);
    k_alpha1<<<(N_NODESC + 255) / 256, 256, 0, stream>>>(x, dw, as1v, ad1v);
    k_agg<HIDC><<<(N_NODESC * 64) / 256, 256, 0, stream>>>(h1, as1v, ad1v, eal1, rowptr,
                                                           src_sorted, b1, dw, x2, as2v,
                                                           ad2v, 1);
    k_h2<<<(N_NODESC + 7) / 8, 256, 0, stream>>>(x2, W2, h2);
    k_agg<OUTCC><<<(N_NODESC * 64) / 256, 256, 0, stream>>>(h2, as2v, ad2v, eal2, rowptr,
                                                            src_sorted, b2, dw, out2,
                                                            nullptr, nullptr, 0);
    k_pool<<<(N_NODESC + 63) / 64, 64, 0, stream>>>(out2, batch, out);
    k_finalize<<<4, 256, 0, stream>>>(batch, out);
}

// Round 3
// 246.985 us; speedup vs baseline: 2.6019x; 1.5015x over previous
//
#include <hip/hip_runtime.h>
#include <math.h>

#define N_NODESC 50000
#define N_EDGESC 800000
#define N_GRAPHSC 16
#define IN_CC 5
#define HIDC 128
#define OUTCC 64

#define SCAN_B 1024
#define NBLK ((N_NODESC + SCAN_B - 1) / SCAN_B)  // 49

// derived-weight buffer layout (floats)
#define DW_WAS1 0
#define DW_WAD1 5
#define DW_WEAE1 10
#define DW_WEAE2 13
#define DW_WAS2 16
#define DW_WAD2 144
#define DW_TOTAL 272

__device__ __forceinline__ float leakyf(float x) { return x >= 0.0f ? x : 0.2f * x; }

// ---------------- derived weights: W@a_s, W@a_d, We@ae ----------------
__global__ void k_derived(const float* __restrict__ W1, const float* __restrict__ as1,
                          const float* __restrict__ ad1, const float* __restrict__ We1,
                          const float* __restrict__ ae1, const float* __restrict__ W2,
                          const float* __restrict__ as2, const float* __restrict__ ad2,
                          const float* __restrict__ We2, const float* __restrict__ ae2,
                          float* __restrict__ dw) {
    for (int t = threadIdx.x; t < DW_TOTAL; t += blockDim.x) {
        float acc = 0.0f;
        if (t < 5) {
            for (int c = 0; c < HIDC; ++c) acc += W1[t * HIDC + c] * as1[c];
        } else if (t < 10) {
            int k = t - 5;
            for (int c = 0; c < HIDC; ++c) acc += W1[k * HIDC + c] * ad1[c];
        } else if (t < 13) {
            int j = t - 10;
            for (int c = 0; c < HIDC; ++c) acc += We1[j * HIDC + c] * ae1[c];
        } else if (t < 16) {
            int j = t - 13;
            for (int c = 0; c < OUTCC; ++c) acc += We2[j * OUTCC + c] * ae2[c];
        } else if (t < 144) {
            int k = t - 16;
            for (int c = 0; c < OUTCC; ++c) acc += W2[k * OUTCC + c] * as2[c];
        } else {
            int k = t - 144;
            for (int c = 0; c < OUTCC; ++c) acc += W2[k * OUTCC + c] * ad2[c];
        }
        dw[t] = acc;
    }
}

// ---------------- edge counting (single int atomic per edge) ----------------
__global__ void k_count(const int* __restrict__ ei, int* __restrict__ cnt) {
    int e = blockIdx.x * blockDim.x + threadIdx.x;
    if (e >= N_EDGESC) return;
    atomicAdd(&cnt[ei[N_EDGESC + e]], 1);
}

// ---------------- hierarchical exclusive scan: cnt -> rowptr ----------------
__global__ void k_scan1(const int* __restrict__ cnt, int* __restrict__ rp,
                        int* __restrict__ bsum) {
    __shared__ int s[SCAN_B];
    int tid = threadIdx.x;
    int idx = blockIdx.x * SCAN_B + tid;
    int v = (idx < N_NODESC) ? cnt[idx] : 0;
    s[tid] = v;
    __syncthreads();
    for (int off = 1; off < SCAN_B; off <<= 1) {
        int t = (tid >= off) ? s[tid - off] : 0;
        __syncthreads();
        s[tid] += t;
        __syncthreads();
    }
    if (idx < N_NODESC) rp[idx] = s[tid] - v;  // exclusive within block
    if (tid == SCAN_B - 1) bsum[blockIdx.x] = s[tid];
}

__global__ void k_scan2(const int* __restrict__ bsum, int* __restrict__ btop) {
    int lane = threadIdx.x;  // one wave
    int orig = (lane < NBLK) ? bsum[lane] : 0;
    int v = orig;
#pragma unroll
    for (int off = 1; off < 64; off <<= 1) {
        int t = __shfl_up(v, off);
        if (lane >= off) v += t;
    }
    if (lane < NBLK) btop[lane] = v - orig;  // exclusive
}

__global__ void k_scan3(int* __restrict__ rp, const int* __restrict__ btop) {
    int idx = blockIdx.x * SCAN_B + threadIdx.x;
    if (idx < N_NODESC) rp[idx] += btop[blockIdx.x];
    if (idx == 0) rp[N_NODESC] = N_EDGESC;
}

// ---------------- alpha_s1/alpha_d1 = x @ (W1@a) ----------------
__global__ void k_alpha1(const float* __restrict__ x, const float* __restrict__ dw,
                         float* __restrict__ as1v, float* __restrict__ ad1v) {
    int n = blockIdx.x * blockDim.x + threadIdx.x;
    if (n >= N_NODESC) return;
    float a = 0.0f, b = 0.0f;
#pragma unroll
    for (int k = 0; k < IN_CC; ++k) {
        float xv = x[n * IN_CC + k];
        a += xv * dw[DW_WAS1 + k];
        b += xv * dw[DW_WAD1 + k];
    }
    as1v[n] = a;
    ad1v[n] = b;
}

// ---------------- scatter edges: one 16B record per edge ----------------
// rec = {src (bits), eal1, eal2, alpha_s1[src]}
__global__ void k_scatter(const int* __restrict__ ei, const float* __restrict__ eattr,
                          const int* __restrict__ rowptr, int* __restrict__ cnt,
                          const float* __restrict__ as1v, float4* __restrict__ edges,
                          const float* __restrict__ dw) {
    int e = blockIdx.x * blockDim.x + threadIdx.x;
    if (e >= N_EDGESC) return;
    int srcn = ei[e];
    int d = ei[N_EDGESC + e];
    int pos = rowptr[d] + atomicSub(&cnt[d], 1) - 1;
    float a0 = eattr[e * 3 + 0], a1 = eattr[e * 3 + 1], a2 = eattr[e * 3 + 2];
    float4 rec;
    rec.x = __int_as_float(srcn);
    rec.y = a0 * dw[DW_WEAE1 + 0] + a1 * dw[DW_WEAE1 + 1] + a2 * dw[DW_WEAE1 + 2];
    rec.z = a0 * dw[DW_WEAE2 + 0] + a1 * dw[DW_WEAE2 + 1] + a2 * dw[DW_WEAE2 + 2];
    rec.w = as1v[srcn];
    edges[pos] = rec;
}

// ---------------- layer-1 aggregate in INPUT space (5 channels) ----------------
// agg1[n] = sum over incoming (+self) of softmax-coef * x[src]
__global__ void k_agg1(const float* __restrict__ x, const float* __restrict__ as1v,
                       const float* __restrict__ ad1v, const float4* __restrict__ edges,
                       const int* __restrict__ rowptr, float* __restrict__ agg1) {
    int gid = blockIdx.x * blockDim.x + threadIdx.x;
    int n = gid >> 6;
    int lane = threadIdx.x & 63;
    if (n >= N_NODESC) return;
    int off = rowptr[n];
    int deg = rowptr[n + 1] - off;
    float ad = ad1v[n];
    float m = -1e30f, den = 0.0f, sum_eal = 0.0f;
    float acc[IN_CC] = {0.0f, 0.0f, 0.0f, 0.0f, 0.0f};
    for (int base = 0; base < deg; base += 64) {
        int i = base + lane;
        bool valid = i < deg;
        float4 er = valid ? edges[off + i] : make_float4(0.0f, 0.0f, 0.0f, 0.0f);
        int s = __float_as_int(er.x);
        float l = valid ? leakyf(er.w + ad + er.y) : -1e30f;
        sum_eal += er.y;
        float cm = l;
#pragma unroll
        for (int d2 = 32; d2; d2 >>= 1) cm = fmaxf(cm, __shfl_xor(cm, d2));
        float nm = fmaxf(m, cm);
        float scale = __expf(m - nm);
        float ex = valid ? __expf(l - nm) : 0.0f;
        float exs = ex;
#pragma unroll
        for (int d2 = 32; d2; d2 >>= 1) exs += __shfl_xor(exs, d2);
        den = den * scale + exs;
        m = nm;
        float xs[IN_CC];
#pragma unroll
        for (int c = 0; c < IN_CC; ++c) xs[c] = x[s * IN_CC + c];  // s=0 when invalid, ex=0
#pragma unroll
        for (int c = 0; c < IN_CC; ++c) {
            float pc = ex * xs[c];
#pragma unroll
            for (int d2 = 32; d2; d2 >>= 1) pc += __shfl_xor(pc, d2);
            acc[c] = acc[c] * scale + pc;
        }
    }
#pragma unroll
    for (int d2 = 32; d2; d2 >>= 1) sum_eal += __shfl_xor(sum_eal, d2);
    float la = sum_eal / fmaxf((float)deg, 1.0f);
    float lself = leakyf(as1v[n] + ad + la);
    float nm = fmaxf(m, lself);
    float scale = __expf(m - nm);
    float es = __expf(lself - nm);
    den = den * scale + es;
    float inv = 1.0f / den;
    if (lane < IN_CC) {
        float v = (acc[0] * scale) * 0.0f;  // placeholder avoided below
    }
    // finalize per channel (uniform values; write from first 5 lanes)
    float outv[IN_CC];
#pragma unroll
    for (int c = 0; c < IN_CC; ++c)
        outv[c] = (acc[c] * scale + es * x[n * IN_CC + c]) * inv;
    if (lane == 0) {
#pragma unroll
        for (int c = 0; c < IN_CC; ++c) agg1[n * IN_CC + c] = outv[c];
    }
}

// ---------------- x2 = relu(agg1 @ W1 + b1), fused alpha_s2/alpha_d2 ----------------
__global__ void k_x2(const float* __restrict__ agg1, const float* __restrict__ W1,
                     const float* __restrict__ b1, const float* __restrict__ dw,
                     float* __restrict__ x2, float* __restrict__ as2v,
                     float* __restrict__ ad2v) {
    int gid = blockIdx.x * blockDim.x + threadIdx.x;
    int n = gid >> 6;
    int lane = threadIdx.x & 63;
    if (n >= N_NODESC) return;
    float a0 = agg1[n * IN_CC + 0], a1 = agg1[n * IN_CC + 1], a2 = agg1[n * IN_CC + 2];
    float a3 = agg1[n * IN_CC + 3], a4 = agg1[n * IN_CC + 4];
    float o0 = b1[lane], o1 = b1[64 + lane];
    o0 += a0 * W1[0 * HIDC + lane] + a1 * W1[1 * HIDC + lane] + a2 * W1[2 * HIDC + lane] +
          a3 * W1[3 * HIDC + lane] + a4 * W1[4 * HIDC + lane];
    o1 += a0 * W1[0 * HIDC + 64 + lane] + a1 * W1[1 * HIDC + 64 + lane] +
          a2 * W1[2 * HIDC + 64 + lane] + a3 * W1[3 * HIDC + 64 + lane] +
          a4 * W1[4 * HIDC + 64 + lane];
    o0 = fmaxf(o0, 0.0f);
    o1 = fmaxf(o1, 0.0f);
    x2[(size_t)n * HIDC + lane] = o0;
    x2[(size_t)n * HIDC + 64 + lane] = o1;
    float a = o0 * dw[DW_WAS2 + lane] + o1 * dw[DW_WAS2 + 64 + lane];
    float b = o0 * dw[DW_WAD2 + lane] + o1 * dw[DW_WAD2 + 64 + lane];
#pragma unroll
    for (int d2 = 32; d2; d2 >>= 1) {
        a += __shfl_xor(a, d2);
        b += __shfl_xor(b, d2);
    }
    if (lane == 0) {
        as2v[n] = a;
        ad2v[n] = b;
    }
}

// ---------------- layer-2 aggregate of x2 (128 ch), float4 x 2-edges-per-iter ----------------
__global__ void k_agg2(const float* __restrict__ x2, const float* __restrict__ as2v,
                       const float* __restrict__ ad2v, const float4* __restrict__ edges,
                       const int* __restrict__ rowptr, float* __restrict__ agg2) {
    int gid = blockIdx.x * blockDim.x + threadIdx.x;
    int n = gid >> 6;
    int lane = threadIdx.x & 63;
    if (n >= N_NODESC) return;
    int off = rowptr[n];
    int deg = rowptr[n + 1] - off;
    float ad = ad2v[n];
    float m = -1e30f, den = 0.0f, sum_eal = 0.0f;
    float4 acc = make_float4(0.0f, 0.0f, 0.0f, 0.0f);
    int q = lane & 31;
    int half = lane >> 5;
    for (int base = 0; base < deg; base += 64) {
        int i = base + lane;
        bool valid = i < deg;
        float4 er = valid ? edges[off + i] : make_float4(0.0f, 0.0f, 0.0f, 0.0f);
        int s = __float_as_int(er.x);
        float ev = er.z;
        float l = valid ? leakyf(as2v[s] + ad + ev) : -1e30f;
        sum_eal += ev;
        float cm = l;
#pragma unroll
        for (int d2 = 32; d2; d2 >>= 1) cm = fmaxf(cm, __shfl_xor(cm, d2));
        float nm = fmaxf(m, cm);
        float scale = __expf(m - nm);
        float ex = valid ? __expf(l - nm) : 0.0f;
        float exs = ex;
#pragma unroll
        for (int d2 = 32; d2; d2 >>= 1) exs += __shfl_xor(exs, d2);
        den = den * scale + exs;
        acc.x *= scale; acc.y *= scale; acc.z *= scale; acc.w *= scale;
        m = nm;
        int lim = min(64, deg - base);
        for (int i2 = 0; i2 < lim; i2 += 2) {
            int j = i2 + half;
            int jc = min(j, lim - 1);
            float cf = __shfl(ex, jc);
            int s2 = __shfl(s, jc);
            if (j >= lim) cf = 0.0f;
            const float4 v = *(const float4*)&x2[(size_t)s2 * HIDC + 4 * q];
            acc.x += cf * v.x;
            acc.y += cf * v.y;
            acc.z += cf * v.z;
            acc.w += cf * v.w;
        }
    }
#pragma unroll
    for (int d2 = 32; d2; d2 >>= 1) sum_eal += __shfl_xor(sum_eal, d2);
    float la = sum_eal / fmaxf((float)deg, 1.0f);
    float lself = leakyf(as2v[n] + ad + la);
    float nm = fmaxf(m, lself);
    float scale = __expf(m - nm);
    float es = __expf(lself - nm);
    den = den * scale + es;
    acc.x *= scale; acc.y *= scale; acc.z *= scale; acc.w *= scale;
    // combine halves: lanes 0-31 and 32-63 hold partials of same channels
    acc.x += __shfl_xor(acc.x, 32);
    acc.y += __shfl_xor(acc.y, 32);
    acc.z += __shfl_xor(acc.z, 32);
    acc.w += __shfl_xor(acc.w, 32);
    if (half == 0) {
        const float4 sv = *(const float4*)&x2[(size_t)n * HIDC + 4 * q];
        float inv = 1.0f / den;
        float4 o;
        o.x = (acc.x + es * sv.x) * inv;
        o.y = (acc.y + es * sv.y) * inv;
        o.z = (acc.z + es * sv.z) * inv;
        o.w = (acc.w + es * sv.w) * inv;
        *(float4*)&agg2[(size_t)n * HIDC + 4 * q] = o;
    }
}

// ---------------- mean pool (128 ch partial sums per 64-node chunk) ----------------
__global__ void k_pool128(const float* __restrict__ agg2, const int* __restrict__ batch,
                          float* __restrict__ psum) {
    int lane = threadIdx.x;  // blockDim = 128
    int base = blockIdx.x * 64;
    float acc = 0.0f;
    int curg = batch[base];
    for (int i = 0; i < 64; ++i) {
        int n = base + i;
        if (n >= N_NODESC) break;
        int g = batch[n];
        if (g != curg) {
            atomicAdd(&psum[curg * HIDC + lane], acc);
            acc = 0.0f;
            curg = g;
        }
        acc += agg2[(size_t)n * HIDC + lane];
    }
    atomicAdd(&psum[curg * HIDC + lane], acc);
}

// ---------------- out[g] = (psum[g]/cnt_g) @ W2 + b2 ----------------
__global__ void k_final(const float* __restrict__ psum, const int* __restrict__ batch,
                        const float* __restrict__ W2, const float* __restrict__ b2,
                        float* __restrict__ out) {
    int t = blockIdx.x * blockDim.x + threadIdx.x;
    if (t >= N_GRAPHSC * OUTCC) return;
    int g = t >> 6, c = t & 63;
    int lo = 0, hi = N_NODESC;
    while (lo < hi) {
        int mid = (lo + hi) >> 1;
        if (batch[mid] < g) lo = mid + 1; else hi = mid;
    }
    int start = lo;
    lo = 0; hi = N_NODESC;
    while (lo < hi) {
        int mid = (lo + hi) >> 1;
        if (batch[mid] <= g) lo = mid + 1; else hi = mid;
    }
    float invc = 1.0f / fmaxf((float)(lo - start), 1.0f);
    float acc = 0.0f;
#pragma unroll 8
    for (int k = 0; k < HIDC; ++k) acc += psum[g * HIDC + k] * W2[k * OUTCC + c];
    out[t] = acc * invc + b2[c];
}

extern "C" void kernel_launch(void* const* d_in, const int* in_sizes, int n_in,
                              void* d_out, int out_size, void* d_ws, size_t ws_size,
                              hipStream_t stream) {
    const float* x     = (const float*)d_in[0];
    const int*   ei    = (const int*)d_in[1];
    const float* eattr = (const float*)d_in[2];
    const int*   batch = (const int*)d_in[3];
    const float* W1  = (const float*)d_in[4];
    const float* as1 = (const float*)d_in[5];
    const float* ad1 = (const float*)d_in[6];
    const float* We1 = (const float*)d_in[7];
    const float* ae1 = (const float*)d_in[8];
    const float* b1  = (const float*)d_in[9];
    const float* W2  = (const float*)d_in[10];
    const float* as2 = (const float*)d_in[11];
    const float* ad2 = (const float*)d_in[12];
    const float* We2 = (const float*)d_in[13];
    const float* ae2 = (const float*)d_in[14];
    const float* b2  = (const float*)d_in[15];
    float* out = (float*)d_out;

    char* ws = (char*)d_ws;
    size_t off = 0;
    auto alloc = [&](size_t bytes) -> void* {
        void* p = ws + off;
        off = (off + bytes + 255) & ~(size_t)255;
        return p;
    };
    float*  dw     = (float*)alloc(DW_TOTAL * 4);
    int*    cnt    = (int*)alloc(N_NODESC * 4);
    int*    rowptr = (int*)alloc((N_NODESC + 1) * 4);
    int*    bsum   = (int*)alloc(NBLK * 4);
    int*    btop   = (int*)alloc(NBLK * 4);
    float4* edges  = (float4*)alloc((size_t)N_EDGESC * 16);
    float*  as1v   = (float*)alloc(N_NODESC * 4);
    float*  ad1v   = (float*)alloc(N_NODESC * 4);
    float*  as2v   = (float*)alloc(N_NODESC * 4);
    float*  ad2v   = (float*)alloc(N_NODESC * 4);
    float*  agg1   = (float*)alloc((size_t)N_NODESC * IN_CC * 4);
    float*  x2     = (float*)alloc((size_t)N_NODESC * HIDC * 4);
    float*  agg2   = (float*)alloc((size_t)N_NODESC * HIDC * 4);
    float*  psum   = (float*)alloc((size_t)N_GRAPHSC * HIDC * 4);

    hipMemsetAsync(cnt, 0, N_NODESC * 4, stream);
    hipMemsetAsync(psum, 0, N_GRAPHSC * HIDC * 4, stream);

    k_derived<<<1, 256, 0, stream>>>(W1, as1, ad1, We1, ae1, W2, as2, ad2, We2, ae2, dw);
    k_count<<<(N_EDGESC + 255) / 256, 256, 0, stream>>>(ei, cnt);
    k_scan1<<<NBLK, SCAN_B, 0, stream>>>(cnt, rowptr, bsum);
    k_scan2<<<1, 64, 0, stream>>>(bsum, btop);
    k_scan3<<<NBLK, SCAN_B, 0, stream>>>(rowptr, btop);
    k_alpha1<<<(N_NODESC + 255) / 256, 256, 0, stream>>>(x, dw, as1v, ad1v);
    k_scatter<<<(N_EDGESC + 255) / 256, 256, 0, stream>>>(ei, eattr, rowptr, cnt, as1v,
                                                          edges, dw);
    k_agg1<<<(N_NODESC * 64) / 256, 256, 0, stream>>>(x, as1v, ad1v, edges, rowptr, agg1);
    k_x2<<<(N_NODESC * 64) / 256, 256, 0, stream>>>(agg1, W1, b1, dw, x2, as2v, ad2v);
    k_agg2<<<(N_NODESC * 64) / 256, 256, 0, stream>>>(x2, as2v, ad2v, edges, rowptr, agg2);
    k_pool128<<<(N_NODESC + 63) / 64, 128, 0, stream>>>(agg2, batch, psum);
    k_final<<<4, 256, 0, stream>>>(psum, batch, W2, b2, out);
}